// Round 1
// baseline (2170.820 us; speedup 1.0000x reference)
//
#include <hip/hip_runtime.h>

#define NN 50000
#define NE 400000
#define NBATCH 8
#define NDIM 32
#define EDIM 16
#define H 128
#define NLAYERS 3

// ---------------- node embedding: h = x @ Wn + bn ----------------
__global__ __launch_bounds__(128) void embed_nodes_kernel(
    const float* __restrict__ x, const float* __restrict__ Wn,
    const float* __restrict__ bn, float* __restrict__ h) {
  __shared__ float Ws[NDIM * H];
  __shared__ float xs[16 * NDIM];
  int j = threadIdx.x;
  int nbase = blockIdx.x * 16;
  for (int r = 0; r < NDIM; ++r) Ws[r * H + j] = Wn[r * H + j];
#pragma unroll
  for (int t = 0; t < 4; ++t) {
    int f = j + t * 128;  // 0..511 = 16 nodes * 32 dims
    xs[f] = x[nbase * NDIM + f];
  }
  __syncthreads();
  float b = bn[j];
  for (int nn = 0; nn < 16; ++nn) {
    float acc = b;
#pragma unroll
    for (int k = 0; k < NDIM; ++k)
      acc = fmaf(xs[nn * NDIM + k], Ws[k * H + j], acc);
    h[(size_t)(nbase + nn) * H + j] = acc;
  }
}

// ---------------- degree histogram over dst ----------------
__global__ __launch_bounds__(256) void degree_kernel(const int* __restrict__ ei,
                                                     int* __restrict__ deg) {
  int e = blockIdx.x * 256 + threadIdx.x;
  if (e < NE) atomicAdd(&deg[ei[NE + e]], 1);
}

// ---------------- precompute folded edge weights ----------------
// Wm[l] : [272][128]  rows 0..255 = mW1[l][0:256], rows 256..271 = We @ mW1[l][256:384]
// bm[l] : [128]       = mb1[l] + be @ mW1[l][256:384]
__global__ __launch_bounds__(128) void precomp_wm_kernel(
    const float* __restrict__ mW1, const float* __restrict__ mb1,
    const float* __restrict__ We, const float* __restrict__ be,
    float* __restrict__ Wm, float* __restrict__ bm) {
  int l = blockIdx.x / 273;
  int r = blockIdx.x % 273;
  int j = threadIdx.x;
  const float* w1 = mW1 + (size_t)l * 384 * H;
  if (r < 256) {
    Wm[((size_t)l * 272 + r) * H + j] = w1[(size_t)r * H + j];
  } else if (r < 272) {
    int i = r - 256;
    float s = 0.f;
    for (int c = 0; c < H; ++c)
      s = fmaf(We[i * H + c], w1[(size_t)(256 + c) * H + j], s);
    Wm[((size_t)l * 272 + r) * H + j] = s;
  } else {
    float s = mb1[l * H + j];
    for (int c = 0; c < H; ++c)
      s = fmaf(be[c], w1[(size_t)(256 + c) * H + j], s);
    bm[l * H + j] = s;
  }
}

// ---------------- precompute folded update weights ----------------
// Wu[l] : [256][128] rows 0..127 = uW1[l][0:128], rows 128..255 = mW2[l] @ uW1[l][128:256]
// va[l] : [128] = mb2[l] @ uW1[l][128:256]
__global__ __launch_bounds__(128) void precomp_wu_kernel(
    const float* __restrict__ uW1, const float* __restrict__ mW2,
    const float* __restrict__ mb2, float* __restrict__ Wu,
    float* __restrict__ va) {
  int l = blockIdx.x / 257;
  int r = blockIdx.x % 257;
  int j = threadIdx.x;
  const float* u1 = uW1 + (size_t)l * 256 * H;
  if (r < 128) {
    Wu[((size_t)l * 256 + r) * H + j] = u1[(size_t)r * H + j];
  } else if (r < 256) {
    int i = r - 128;
    const float* m2 = mW2 + ((size_t)l * H + i) * H;
    float s = 0.f;
    for (int c = 0; c < H; ++c)
      s = fmaf(m2[c], u1[(size_t)(128 + c) * H + j], s);
    Wu[((size_t)l * 256 + r) * H + j] = s;
  } else {
    float s = 0.f;
    for (int c = 0; c < H; ++c)
      s = fmaf(mb2[l * H + c], u1[(size_t)(128 + c) * H + j], s);
    va[l * H + j] = s;
  }
}

// ---------------- fused edge MLP + scatter-add of relu(hidden) ----------------
__global__ __launch_bounds__(256) void edge_mlp_kernel(
    const float* __restrict__ h, const int* __restrict__ ei,
    const float* __restrict__ ea, const float* __restrict__ Wm,
    const float* __restrict__ bm, float* __restrict__ aggrH) {
  __shared__ float ins[16][272];  // [h_dst(128) | h_src(128) | ea(16)]
  __shared__ int dstS[16], srcS[16];
  int tid = threadIdx.x;
  int ebase = blockIdx.x * 16;
  if (tid < 16) {
    srcS[tid] = ei[ebase + tid];
    dstS[tid] = ei[NE + ebase + tid];
  }
  __syncthreads();
#pragma unroll
  for (int t = 0; t < 4; ++t) {
    int f = tid + t * 256;          // 0..1023 float4 slots
    int r = f >> 5, c4 = f & 31;    // 32 rows x 32 float4
    int node = (r < 16) ? dstS[r] : srcS[r - 16];
    float4 v = ((const float4*)(h + (size_t)node * H))[c4];
    float* q = (r < 16) ? &ins[r][c4 * 4] : &ins[r - 16][H + c4 * 4];
    *(float4*)q = v;
  }
  if (tid < 64) {
    int te = tid >> 2, c4 = tid & 3;
    float4 v = ((const float4*)(ea + (size_t)(ebase + te) * EDIM))[c4];
    *(float4*)&ins[te][2 * H + c4 * 4] = v;
  }
  __syncthreads();
  int j = tid & 127;
  int e0 = (tid >> 7) * 8;
  float acc[8];
  float b = bm[j];
#pragma unroll
  for (int e = 0; e < 8; ++e) acc[e] = b;
  for (int k = 0; k < 272; k += 4) {
    float w0 = Wm[(size_t)(k + 0) * H + j];
    float w1 = Wm[(size_t)(k + 1) * H + j];
    float w2 = Wm[(size_t)(k + 2) * H + j];
    float w3 = Wm[(size_t)(k + 3) * H + j];
#pragma unroll
    for (int e = 0; e < 8; ++e) {
      float4 v = *(const float4*)&ins[e0 + e][k];
      acc[e] = fmaf(v.x, w0, acc[e]);
      acc[e] = fmaf(v.y, w1, acc[e]);
      acc[e] = fmaf(v.z, w2, acc[e]);
      acc[e] = fmaf(v.w, w3, acc[e]);
    }
  }
#pragma unroll
  for (int e = 0; e < 8; ++e) {
    float v = fmaxf(acc[e], 0.f);
    unsafeAtomicAdd(&aggrH[(size_t)dstS[e0 + e] * H + j], v);
  }
}

// ---------------- fused node update ----------------
__global__ __launch_bounds__(256) void node_update_kernel(
    float* __restrict__ h, const float* __restrict__ aggrH,
    const int* __restrict__ deg, const float* __restrict__ Wu,
    const float* __restrict__ va, const float* __restrict__ ub1,
    const float* __restrict__ uW2, const float* __restrict__ ub2) {
  __shared__ float ins[16][256];  // [h(128) | aggrH(128)]
  __shared__ float ts[16][128];
  __shared__ float degS[16];
  int tid = threadIdx.x;
  int nbase = blockIdx.x * 16;
  if (tid < 16) degS[tid] = (float)deg[nbase + tid];
#pragma unroll
  for (int t = 0; t < 4; ++t) {
    int f = tid + t * 256;
    int r = f >> 5, c4 = f & 31;
    const float* s = (r < 16) ? (h + (size_t)(nbase + r) * H)
                              : (aggrH + (size_t)(nbase + r - 16) * H);
    float4 v = ((const float4*)s)[c4];
    float* q = (r < 16) ? &ins[r][c4 * 4] : &ins[r - 16][H + c4 * 4];
    *(float4*)q = v;
  }
  __syncthreads();
  int j = tid & 127;
  int n0 = (tid >> 7) * 8;
  float acc[8];
  {
    float b = ub1[j], vaj = va[j];
#pragma unroll
    for (int e = 0; e < 8; ++e) acc[e] = fmaf(degS[n0 + e], vaj, b);
  }
  for (int k = 0; k < 256; k += 4) {
    float w0 = Wu[(size_t)(k + 0) * H + j];
    float w1 = Wu[(size_t)(k + 1) * H + j];
    float w2 = Wu[(size_t)(k + 2) * H + j];
    float w3 = Wu[(size_t)(k + 3) * H + j];
#pragma unroll
    for (int e = 0; e < 8; ++e) {
      float4 v = *(const float4*)&ins[n0 + e][k];
      acc[e] = fmaf(v.x, w0, acc[e]);
      acc[e] = fmaf(v.y, w1, acc[e]);
      acc[e] = fmaf(v.z, w2, acc[e]);
      acc[e] = fmaf(v.w, w3, acc[e]);
    }
  }
#pragma unroll
  for (int e = 0; e < 8; ++e) ts[n0 + e][j] = fmaxf(acc[e], 0.f);
  __syncthreads();
  {
    float b2 = ub2[j];
#pragma unroll
    for (int e = 0; e < 8; ++e) acc[e] = b2;
  }
  for (int k = 0; k < 128; k += 4) {
    float w0 = uW2[(size_t)(k + 0) * H + j];
    float w1 = uW2[(size_t)(k + 1) * H + j];
    float w2 = uW2[(size_t)(k + 2) * H + j];
    float w3 = uW2[(size_t)(k + 3) * H + j];
#pragma unroll
    for (int e = 0; e < 8; ++e) {
      float4 v = *(const float4*)&ts[n0 + e][k];
      acc[e] = fmaf(v.x, w0, acc[e]);
      acc[e] = fmaf(v.y, w1, acc[e]);
      acc[e] = fmaf(v.z, w2, acc[e]);
      acc[e] = fmaf(v.w, w3, acc[e]);
    }
  }
#pragma unroll
  for (int e = 0; e < 8; ++e) {
    size_t idx = (size_t)(nbase + n0 + e) * H + j;
    h[idx] += acc[e];
  }
}

// ---------------- batch mean pooling (batch is sorted) ----------------
__global__ __launch_bounds__(128) void pool_kernel(
    const float* __restrict__ h, const int* __restrict__ batch,
    float* __restrict__ pooled, int* __restrict__ counts) {
  int j = threadIdx.x;
  int nbase = blockIdx.x * 128;
  int nend = nbase + 128;
  if (nend > NN) nend = NN;
  int cur = batch[nbase];
  float sum = 0.f;
  int cnt = 0;
  for (int n = nbase; n < nend; ++n) {
    int b = batch[n];
    if (b != cur) {
      unsafeAtomicAdd(&pooled[cur * H + j], sum);
      if (j == 0) atomicAdd(&counts[cur], cnt);
      sum = 0.f; cnt = 0; cur = b;
    }
    sum += h[(size_t)n * H + j];
    cnt++;
  }
  unsafeAtomicAdd(&pooled[cur * H + j], sum);
  if (j == 0) atomicAdd(&counts[cur], cnt);
}

// ---------------- readout MLP ----------------
__global__ __launch_bounds__(128) void readout_kernel(
    const float* __restrict__ pooled, const int* __restrict__ counts,
    const float* __restrict__ gf, const float* __restrict__ Wg,
    const float* __restrict__ bg, const float* __restrict__ rW1,
    const float* __restrict__ rb1, const float* __restrict__ rW2,
    const float* __restrict__ rb2, const float* __restrict__ rW3,
    const float* __restrict__ rb3, float* __restrict__ out) {
  __shared__ float fin[256];
  __shared__ float t1[128];
  __shared__ float t2[64];
  int j = threadIdx.x;
  for (int b = 0; b < NBATCH; ++b) {
    float cnt = (float)counts[b];
    if (cnt < 1.f) cnt = 1.f;
    fin[j] = pooled[b * H + j] / cnt;
    fin[H + j] = fmaf(gf[b], Wg[j], bg[j]);
    __syncthreads();
    float a = rb1[j];
    for (int k = 0; k < 256; ++k) a = fmaf(fin[k], rW1[k * H + j], a);
    t1[j] = fmaxf(a, 0.f);
    __syncthreads();
    if (j < 64) {
      float a2 = rb2[j];
      for (int k = 0; k < 128; ++k) a2 = fmaf(t1[k], rW2[k * 64 + j], a2);
      t2[j] = fmaxf(a2, 0.f);
    }
    __syncthreads();
    if (j < 64) {
      float p = t2[j] * rW3[j];
#pragma unroll
      for (int off = 32; off; off >>= 1) p += __shfl_down(p, off);
      if (j == 0) out[b] = p + rb3[0];
    }
    __syncthreads();
  }
}

extern "C" void kernel_launch(void* const* d_in, const int* in_sizes, int n_in,
                              void* d_out, int out_size, void* d_ws, size_t ws_size,
                              hipStream_t stream) {
  const float* x   = (const float*)d_in[0];
  const float* ea  = (const float*)d_in[1];
  const float* gf  = (const float*)d_in[2];
  const int*   ei  = (const int*)d_in[3];
  const int*   bat = (const int*)d_in[4];
  const float* Wn  = (const float*)d_in[5];
  const float* bn  = (const float*)d_in[6];
  const float* We  = (const float*)d_in[7];
  const float* be  = (const float*)d_in[8];
  const float* Wg  = (const float*)d_in[9];
  const float* bg  = (const float*)d_in[10];
  const float* mW1 = (const float*)d_in[11];
  const float* mb1 = (const float*)d_in[12];
  const float* mW2 = (const float*)d_in[13];
  const float* mb2 = (const float*)d_in[14];
  const float* uW1 = (const float*)d_in[15];
  const float* ub1 = (const float*)d_in[16];
  const float* uW2 = (const float*)d_in[17];
  const float* ub2 = (const float*)d_in[18];
  const float* rW1 = (const float*)d_in[19];
  const float* rb1 = (const float*)d_in[20];
  const float* rW2 = (const float*)d_in[21];
  const float* rb2 = (const float*)d_in[22];
  const float* rW3 = (const float*)d_in[23];
  const float* rb3 = (const float*)d_in[24];

  char* p = (char*)d_ws;
  float* h     = (float*)p; p += (size_t)NN * H * 4;        // 25.6 MB
  float* aggrH = (float*)p; p += (size_t)NN * H * 4;        // 25.6 MB
  float* Wm    = (float*)p; p += (size_t)NLAYERS * 272 * H * 4;
  float* bm    = (float*)p; p += (size_t)NLAYERS * H * 4;
  float* Wu    = (float*)p; p += (size_t)NLAYERS * 256 * H * 4;
  float* va    = (float*)p; p += (size_t)NLAYERS * H * 4;
  int*   deg   = (int*)p;   p += (size_t)NN * 4;
  float* pooled= (float*)p; p += (size_t)NBATCH * H * 4;
  int*   counts= (int*)p;   p += 64;

  hipMemsetAsync(deg, 0, (size_t)NN * 4, stream);
  hipMemsetAsync(pooled, 0, (size_t)NBATCH * H * 4, stream);
  hipMemsetAsync(counts, 0, 64, stream);

  embed_nodes_kernel<<<NN / 16, 128, 0, stream>>>(x, Wn, bn, h);
  degree_kernel<<<(NE + 255) / 256, 256, 0, stream>>>(ei, deg);
  precomp_wm_kernel<<<NLAYERS * 273, 128, 0, stream>>>(mW1, mb1, We, be, Wm, bm);
  precomp_wu_kernel<<<NLAYERS * 257, 128, 0, stream>>>(uW1, mW2, mb2, Wu, va);

  for (int l = 0; l < NLAYERS; ++l) {
    hipMemsetAsync(aggrH, 0, (size_t)NN * H * 4, stream);
    edge_mlp_kernel<<<NE / 16, 256, 0, stream>>>(
        h, ei, ea, Wm + (size_t)l * 272 * H, bm + (size_t)l * H, aggrH);
    node_update_kernel<<<NN / 16, 256, 0, stream>>>(
        h, aggrH, deg, Wu + (size_t)l * 256 * H, va + (size_t)l * H,
        ub1 + (size_t)l * H, uW2 + (size_t)l * H * H, ub2 + (size_t)l * H);
  }

  pool_kernel<<<(NN + 127) / 128, 128, 0, stream>>>(h, bat, pooled, counts);
  readout_kernel<<<1, 128, 0, stream>>>(pooled, counts, gf, Wg, bg, rW1, rb1,
                                        rW2, rb2, rW3, rb3, (float*)d_out);
}